// Round 16
// baseline (168.933 us; speedup 1.0000x reference)
//
#include <hip/hip_runtime.h>
#include <math.h>

#define BB 32

typedef __attribute__((ext_vector_type(8))) short bf16x8;
typedef __attribute__((ext_vector_type(4))) short bf16x4;
typedef __attribute__((ext_vector_type(4))) float f32x4;

__device__ __forceinline__ unsigned short f2b(float x) {
    unsigned u = __float_as_uint(x);
    u += 0x7fffu + ((u >> 16) & 1u);     // RNE; inputs finite
    return (unsigned short)(u >> 16);
}

// ---------------- prep: render NHWC bf16 + prepack all weights + cnt=0 ------
__global__ __launch_bounds__(256) void prep_kernel(
        const float* __restrict__ x, unsigned short* __restrict__ lay,
        const float* __restrict__ w1, const float* __restrict__ w2,
        const float* __restrict__ w3,
        unsigned short* __restrict__ wp1, unsigned short* __restrict__ wp2,
        unsigned short* __restrict__ wp3, int* __restrict__ cnt) {
    int bid = blockIdx.x;
    if (bid == 0 && threadIdx.x < 32) cnt[threadIdx.x] = 0;
    if (bid < 512) {
        int b = bid >> 4;
        int u = ((bid & 15) << 2) + (threadIdx.x >> 6);
        int n = threadIdx.x & 63;
        const float* xp = x + ((size_t)b * 64 + n) * 20;
        int xL = (int)xp[0], yT = (int)xp[1], xR = (int)xp[2], yB = (int)xp[3];
        float m = xp[4];
        #pragma unroll
        for (int c = 1; c < 16; ++c) m = fmaxf(m, xp[4 + c]);
        unsigned short mu = f2b(m);
        unsigned short* op = lay + (((size_t)b * 64 + u) * 64) * 64 + n;
        #pragma unroll 4
        for (int v = 0; v < 64; ++v) {
            bool vb = (u < 63) && (v < 63) &&
                      (((u == xL || u == xR) && (v > yT && v < yB)) ||
                       ((v == yT || v == yB) && (u > xL && u < xR)));
            op[(size_t)v * 64] = vb ? mu : (unsigned short)0;
        }
    } else {
        int idx = (bid - 512) * 256 + threadIdx.x;
        const int N1 = 64 * 576, N2 = 128 * 576, N3 = 128 * 1152;
        if (idx < N1) {
            int co = idx / 576, k = idx - co * 576;
            int r = k / 64, ci = k - r * 64;
            wp1[idx] = f2b(w1[((size_t)co * 64 + ci) * 9 + r]);
        } else if (idx < N1 + N2) {
            int i2 = idx - N1;
            int co = i2 / 576, k = i2 - co * 576;
            int r = k / 64, ci = k - r * 64;
            wp2[i2] = f2b(w2[((size_t)co * 64 + ci) * 9 + r]);
        } else if (idx < N1 + N2 + N3) {
            int i3 = idx - N1 - N2;
            int co = i3 / 1152, k = i3 - co * 1152;
            int r = k / 128, ci = k - r * 128;
            wp3[i3] = f2b(w3[((size_t)co * 128 + ci) * 9 + r]);
        }
    }
}

// ---------------- MFMA implicit-GEMM conv 3x3 stride-2 VALID ----------------
// src bf16 NHWC [B][SR][SC][CIN]. Epilogue fuses per-block BN stats partials.
template<int CIN, int COUT, int SR, int SC, int HOUT, int OCP, int RG,
         int RGP, int MGN>
__global__ __launch_bounds__(256) void gemmconv_kernel(
        const unsigned short* __restrict__ src,
        const unsigned short* __restrict__ wp,
        const float* __restrict__ bias,
        float* __restrict__ out,          // f32 raw [B][COUT][HOUT^2]
        float* __restrict__ psum,         // [COUT][PBLK]
        float* __restrict__ psq) {
    constexpr int K    = 9 * CIN;
    constexpr int NTB  = RGP * OCP / 16;
    constexpr int STR  = 2 * RGP + 1;
    constexpr int STC  = 2 * OCP + 1;
    constexpr int CIP  = 36;
    constexpr int MTB  = COUT / 16 / MGN;
    constexpr int NRG  = (HOUT + RG - 1) / RG;
    constexpr int PBLK = BB * NRG;

    __shared__ unsigned short stage[STR * STC * CIP];

    int tid = threadIdx.x;
    int wv = tid >> 6, lane = tid & 63;
    int l15 = lane & 15, lg = lane >> 4;
    int bid = blockIdx.x;
    int b  = bid & 31;
    int t2 = bid >> 5;
    int rg = t2 % NRG;
    int mg = t2 / NRG;
    int co0 = mg * (COUT / MGN);
    int mw = wv % MTB;

    f32x4 acc[NTB];
    #pragma unroll
    for (int i = 0; i < NTB; ++i) acc[i] = (f32x4){0.f, 0.f, 0.f, 0.f};

    const unsigned short* srcb = src + (size_t)b * SR * SC * CIN;
    int srow0 = 2 * rg * RG;

    for (int cb = 0; cb < CIN / 32; ++cb) {
        __syncthreads();
        for (int idx = tid; idx < STR * STC * 16; idx += 256) {
            int ci2 = idx & 15;
            int rc  = idx >> 4;
            int row = rc / STC, col = rc - row * STC;
            int srow = srow0 + row;
            unsigned v = 0;
            if (srow < SR && col < SC)
                v = *(const unsigned*)(srcb + ((size_t)srow * SC + col) * CIN
                                       + cb * 32 + ci2 * 2);
            *(unsigned*)(stage + (row * STC + col) * CIP + ci2 * 2) = v;
        }
        __syncthreads();
        #pragma unroll
        for (int r = 0; r < 9; ++r) {
            int ky = r / 3, kx = r % 3;
            int kk = r * CIN + cb * 32 + lg * 8;
            bf16x8 af = *(const bf16x8*)(wp + (size_t)(co0 + mw * 16 + l15) * K + kk);
            #pragma unroll
            for (int nt = 0; nt < NTB; ++nt) {
                int n = nt * 16 + l15;
                int dy = n / OCP, oxx = n % OCP;
                const unsigned short* sp =
                    stage + ((2 * dy + ky) * STC + (2 * oxx + kx)) * CIP + lg * 8;
                bf16x4 blo = *(const bf16x4*)sp;
                bf16x4 bhi = *(const bf16x4*)(sp + 4);
                bf16x8 bfr;
                bfr[0] = blo[0]; bfr[1] = blo[1]; bfr[2] = blo[2]; bfr[3] = blo[3];
                bfr[4] = bhi[0]; bfr[5] = bhi[1]; bfr[6] = bhi[2]; bfr[7] = bhi[3];
                acc[nt] = __builtin_amdgcn_mfma_f32_16x16x32_bf16(af, bfr, acc[nt], 0, 0, 0);
            }
        }
    }

    // epilogue: write raw out + fused per-block stats partials
    float sa[4] = {0.f, 0.f, 0.f, 0.f}, qa[4] = {0.f, 0.f, 0.f, 0.f};
    #pragma unroll
    for (int nt = 0; nt < NTB; ++nt) {
        int n = nt * 16 + l15;
        int oy = rg * RG + n / OCP, oxx = n % OCP;
        bool act = (oy < HOUT) && (oxx < HOUT);
        #pragma unroll
        for (int q = 0; q < 4; ++q) {
            int co = co0 + mw * 16 + lg * 4 + q;
            float v = act ? (acc[nt][q] + bias[co]) : 0.f;
            if (act)
                out[((size_t)b * COUT + co) * (HOUT * HOUT) + oy * HOUT + oxx] = v;
            sa[q] += v; qa[q] += v * v;
        }
    }
    #pragma unroll
    for (int o = 1; o < 16; o <<= 1) {
        #pragma unroll
        for (int q = 0; q < 4; ++q) {
            sa[q] += __shfl_xor(sa[q], o, 64);
            qa[q] += __shfl_xor(qa[q], o, 64);
        }
    }
    if (l15 == 0) {
        int pblk = b * NRG + rg;
        #pragma unroll
        for (int q = 0; q < 4; ++q) {
            int co = co0 + mw * 16 + lg * 4 + q;
            psum[(size_t)co * PBLK + pblk] = sa[q];
            psq [(size_t)co * PBLK + pblk] = qa[q];
        }
    }
}

// ---------------- fold partials -> scale/shift (one block per channel) ------
__global__ __launch_bounds__(256) void stats_fold_kernel(
        const float* __restrict__ psum, const float* __restrict__ psq,
        const float* __restrict__ g, const float* __restrict__ be,
        float* __restrict__ scale, float* __restrict__ shift,
        int PBLK, float count) {
    int c = blockIdx.x;
    float S = 0.f, Q = 0.f;
    for (int p = threadIdx.x; p < PBLK; p += 256) {
        S += psum[(size_t)c * PBLK + p];
        Q += psq[(size_t)c * PBLK + p];
    }
    __shared__ float rs[4], rq[4];
    int lane = threadIdx.x & 63, wv = threadIdx.x >> 6;
    #pragma unroll
    for (int o = 32; o > 0; o >>= 1) {
        S += __shfl_down(S, o, 64);
        Q += __shfl_down(Q, o, 64);
    }
    if (lane == 0) { rs[wv] = S; rq[wv] = Q; }
    __syncthreads();
    if (threadIdx.x == 0) {
        float St = rs[0] + rs[1] + rs[2] + rs[3];
        float Qt = rq[0] + rq[1] + rq[2] + rq[3];
        float mean = St / count;
        float var  = Qt / count - mean * mean;
        float sc   = g[c] * rsqrtf(var + 1e-5f);
        scale[c] = sc;
        shift[c] = be[c] - mean * sc;
    }
}

// ---------------- BN+ReLU + transpose to NHWC bf16 (col-padded) -------------
template<int C, int R, int SCo>
__global__ __launch_bounds__(256) void applyT_kernel(
        const float* __restrict__ raw, const float* __restrict__ scale,
        const float* __restrict__ shift, unsigned short* __restrict__ act) {
    int b = blockIdx.x / R, row = blockIdx.x % R;
    __shared__ float lds[C * (R + 2)];
    for (int idx = threadIdx.x; idx < C * R; idx += 256) {
        int ci = idx / R, col = idx - ci * R;
        float v = fmaxf(fmaf(raw[((size_t)b * C + ci) * (R * R) + row * R + col],
                             scale[ci], shift[ci]), 0.f);
        lds[ci * (R + 2) + col] = v;
    }
    __syncthreads();
    for (int idx = threadIdx.x; idx < SCo * C; idx += 256) {
        int col = idx / C, ci = idx - col * C;
        unsigned short v = 0;
        if (col < R) v = f2b(lds[ci * (R + 2) + col]);
        act[(((size_t)b * R + row) * SCo + col) * C + ci] = v;
    }
}

// ---------------- FC head: fold3 + BN+ReLU + fc1 + (last block) fc2 --------
__global__ __launch_bounds__(256) void fc1_kernel(
        const float* __restrict__ out3,   // [B][128][49] raw
        const float* __restrict__ psum,   // [128][32] conv3 partials
        const float* __restrict__ psq,
        const float* __restrict__ g3, const float* __restrict__ be3,
        const float* __restrict__ fc1w,   // [64][6272]
        const float* __restrict__ fc1b,
        const float* __restrict__ fc2w,   // [64]
        const float* __restrict__ fc2b,   // [1]
        float* __restrict__ h,            // [B][64]
        int* __restrict__ cnt,            // [B]
        float* __restrict__ outp) {       // [B]
    __shared__ float sc[128], sh[128];
    __shared__ float red[4];
    __shared__ int winner;
    int j = blockIdx.x >> 5;
    int b = blockIdx.x & 31;

    // fold3 (replicated per block; 8K L2 loads)
    for (int c = threadIdx.x; c < 128; c += 256) {
        float S = 0.f, Q = 0.f;
        #pragma unroll
        for (int p = 0; p < 32; ++p) {
            S += psum[c * 32 + p];
            Q += psq[c * 32 + p];
        }
        const float count = 32.f * 49.f;
        float mean = S / count;
        float var  = Q / count - mean * mean;
        float s = g3[c] * rsqrtf(var + 1e-5f);
        sc[c] = s;
        sh[c] = be3[c] - mean * s;
    }
    __syncthreads();

    const float* ip = out3 + (size_t)b * 6272;
    const float* wp = fc1w + (size_t)j * 6272;
    float s = 0.f;
    for (int i = threadIdx.x; i < 6272; i += 256) {
        int c = i / 49;
        float xv = fmaxf(fmaf(ip[i], sc[c], sh[c]), 0.f);
        s = fmaf(xv, wp[i], s);
    }
    #pragma unroll
    for (int o = 32; o > 0; o >>= 1) s += __shfl_down(s, o, 64);
    if ((threadIdx.x & 63) == 0) red[threadIdx.x >> 6] = s;
    __syncthreads();
    if (threadIdx.x == 0) {
        float t = red[0] + red[1] + red[2] + red[3];
        __hip_atomic_store(&h[b * 64 + j], fmaxf(t + fc1b[j], 0.f),
                           __ATOMIC_RELAXED, __HIP_MEMORY_SCOPE_AGENT);
        __threadfence();
        int old = __hip_atomic_fetch_add(&cnt[b], 1, __ATOMIC_ACQ_REL,
                                         __HIP_MEMORY_SCOPE_AGENT);
        winner = (old == 63) ? 1 : 0;
    }
    __syncthreads();
    if (winner && threadIdx.x < 64) {
        __threadfence();
        float v = __hip_atomic_load(&h[b * 64 + threadIdx.x], __ATOMIC_RELAXED,
                                    __HIP_MEMORY_SCOPE_AGENT) * fc2w[threadIdx.x];
        #pragma unroll
        for (int o = 32; o > 0; o >>= 1) v += __shfl_down(v, o, 64);
        if (threadIdx.x == 0)
            outp[b] = 1.f / (1.f + expf(-(v + fc2b[0])));
    }
}

// ---------------- Launch ----------------
extern "C" void kernel_launch(void* const* d_in, const int* in_sizes, int n_in,
                              void* d_out, int out_size, void* d_ws, size_t ws_size,
                              hipStream_t stream) {
    const float* x       = (const float*)d_in[0];
    const float* conv1_w = (const float*)d_in[1];
    const float* conv1_b = (const float*)d_in[2];
    const float* bn1_g   = (const float*)d_in[3];
    const float* bn1_b   = (const float*)d_in[4];
    const float* conv2_w = (const float*)d_in[5];
    const float* conv2_b = (const float*)d_in[6];
    const float* bn2_g   = (const float*)d_in[7];
    const float* bn2_b   = (const float*)d_in[8];
    const float* conv3_w = (const float*)d_in[9];
    const float* conv3_b = (const float*)d_in[10];
    const float* bn3_g   = (const float*)d_in[11];
    const float* bn3_b   = (const float*)d_in[12];
    const float* fc1_w   = (const float*)d_in[13];
    const float* fc1_b   = (const float*)d_in[14];
    const float* fc2_w   = (const float*)d_in[15];
    const float* fc2_b   = (const float*)d_in[16];
    float* out = (float*)d_out;

    char* wsc = (char*)d_ws;
    size_t o = 0;
    auto alloc = [&](size_t bytes) { char* p = wsc + o; o += (bytes + 255) & ~(size_t)255; return p; };
    unsigned short* laybf  = (unsigned short*)alloc((size_t)BB * 64 * 64 * 64 * 2);
    unsigned short* act1bf = (unsigned short*)alloc((size_t)BB * 31 * 32 * 64 * 2);
    unsigned short* act2bf = (unsigned short*)alloc((size_t)BB * 15 * 16 * 128 * 2);
    unsigned short* wp1    = (unsigned short*)alloc((size_t)64 * 576 * 2);
    unsigned short* wp2    = (unsigned short*)alloc((size_t)128 * 576 * 2);
    unsigned short* wp3    = (unsigned short*)alloc((size_t)128 * 1152 * 2);
    float* out1   = (float*)alloc((size_t)BB * 64 * 961 * 4);
    float* out2   = (float*)alloc((size_t)BB * 128 * 225 * 4);
    float* out3   = (float*)alloc((size_t)BB * 128 * 49 * 4);
    float* psum   = (float*)alloc((size_t)128 * 512 * 4);
    float* psq    = (float*)alloc((size_t)128 * 512 * 4);
    float* scale1 = (float*)alloc(64 * 4);
    float* shift1 = (float*)alloc(64 * 4);
    float* scale2 = (float*)alloc(128 * 4);
    float* shift2 = (float*)alloc(128 * 4);
    float* hbuf   = (float*)alloc((size_t)BB * 64 * 4);
    int*   cnt    = (int*)alloc((size_t)BB * 4);

    // 1) render + weight prepack + cnt reset
    prep_kernel<<<1520, 256, 0, stream>>>(x, laybf, conv1_w, conv2_w, conv3_w,
                                          wp1, wp2, wp3, cnt);

    // 2) conv1 (bf16 NHWC) + fused stats partials. grid 32*16
    gemmconv_kernel<64, 64, 64, 64, 31, 32, 2, 2, 1>
        <<<32 * 16, 256, 0, stream>>>(laybf, wp1, conv1_b, out1, psum, psq);
    stats_fold_kernel<<<64, 256, 0, stream>>>(psum, psq, bn1_g, bn1_b,
                                              scale1, shift1, 32 * 16,
                                              (float)(BB * 961));
    applyT_kernel<64, 31, 32><<<BB * 31, 256, 0, stream>>>(out1, scale1, shift1, act1bf);

    // 3) conv2 (bf16 NHWC) + fused stats partials. grid 32*16
    gemmconv_kernel<64, 128, 31, 32, 15, 16, 2, 2, 2>
        <<<32 * 16, 256, 0, stream>>>(act1bf, wp2, conv2_b, out2, psum, psq);
    stats_fold_kernel<<<128, 256, 0, stream>>>(psum, psq, bn2_g, bn2_b,
                                               scale2, shift2, 32 * 8,
                                               (float)(BB * 225));
    applyT_kernel<128, 15, 16><<<BB * 15, 256, 0, stream>>>(out2, scale2, shift2, act2bf);

    // 4) conv3 (bf16 NHWC) + fused stats partials. grid 32*2
    gemmconv_kernel<128, 128, 15, 16, 7, 8, 7, 8, 2>
        <<<32 * 2, 256, 0, stream>>>(act2bf, wp3, conv3_b, out3, psum, psq);

    // 5) FC head: fold3 + fc1 + last-block fc2 in one kernel
    fc1_kernel<<<64 * 32, 256, 0, stream>>>(out3, psum, psq, bn3_g, bn3_b,
                                            fc1_w, fc1_b, fc2_w, fc2_b,
                                            hbuf, cnt, out);
}

// Round 17
// 161.235 us; speedup vs baseline: 1.0477x; 1.0477x over previous
//
#include <hip/hip_runtime.h>
#include <math.h>

#define BB 32

typedef __attribute__((ext_vector_type(8))) short bf16x8;
typedef __attribute__((ext_vector_type(4))) short bf16x4;
typedef __attribute__((ext_vector_type(4))) float f32x4;

__device__ __forceinline__ unsigned short f2b(float x) {
    unsigned u = __float_as_uint(x);
    u += 0x7fffu + ((u >> 16) & 1u);     // RNE; inputs finite
    return (unsigned short)(u >> 16);
}

// ---------------- prep: render NHWC bf16 + prepack all weights + cnt=0 ------
__global__ __launch_bounds__(256) void prep_kernel(
        const float* __restrict__ x, unsigned short* __restrict__ lay,
        const float* __restrict__ w1, const float* __restrict__ w2,
        const float* __restrict__ w3,
        unsigned short* __restrict__ wp1, unsigned short* __restrict__ wp2,
        unsigned short* __restrict__ wp3, int* __restrict__ cnt) {
    int bid = blockIdx.x;
    if (bid == 0 && threadIdx.x < 32) cnt[threadIdx.x] = 0;
    if (bid < 512) {
        int b = bid >> 4;
        int u = ((bid & 15) << 2) + (threadIdx.x >> 6);
        int n = threadIdx.x & 63;
        const float* xp = x + ((size_t)b * 64 + n) * 20;
        int xL = (int)xp[0], yT = (int)xp[1], xR = (int)xp[2], yB = (int)xp[3];
        float m = xp[4];
        #pragma unroll
        for (int c = 1; c < 16; ++c) m = fmaxf(m, xp[4 + c]);
        unsigned short mu = f2b(m);
        unsigned short* op = lay + (((size_t)b * 64 + u) * 64) * 64 + n;
        #pragma unroll 4
        for (int v = 0; v < 64; ++v) {
            bool vb = (u < 63) && (v < 63) &&
                      (((u == xL || u == xR) && (v > yT && v < yB)) ||
                       ((v == yT || v == yB) && (u > xL && u < xR)));
            op[(size_t)v * 64] = vb ? mu : (unsigned short)0;
        }
    } else {
        int idx = (bid - 512) * 256 + threadIdx.x;
        const int N1 = 64 * 576, N2 = 128 * 576, N3 = 128 * 1152;
        if (idx < N1) {
            int co = idx / 576, k = idx - co * 576;
            int r = k / 64, ci = k - r * 64;
            wp1[idx] = f2b(w1[((size_t)co * 64 + ci) * 9 + r]);
        } else if (idx < N1 + N2) {
            int i2 = idx - N1;
            int co = i2 / 576, k = i2 - co * 576;
            int r = k / 64, ci = k - r * 64;
            wp2[i2] = f2b(w2[((size_t)co * 64 + ci) * 9 + r]);
        } else if (idx < N1 + N2 + N3) {
            int i3 = idx - N1 - N2;
            int co = i3 / 1152, k = i3 - co * 1152;
            int r = k / 128, ci = k - r * 128;
            wp3[i3] = f2b(w3[((size_t)co * 128 + ci) * 9 + r]);
        }
    }
}

// ---------------- MFMA implicit-GEMM conv 3x3 stride-2 VALID ----------------
// src bf16 NHWC [B][SR][SC][CIN]. Epilogue fuses per-block BN stats partials.
// PTRANS: partials stored [PBLK][COUT] (coalesced channel-major consumption).
template<int CIN, int COUT, int SR, int SC, int HOUT, int OCP, int RG,
         int RGP, int MGN, bool PTRANS>
__global__ __launch_bounds__(256) void gemmconv_kernel(
        const unsigned short* __restrict__ src,
        const unsigned short* __restrict__ wp,
        const float* __restrict__ bias,
        float* __restrict__ out,          // f32 raw [B][COUT][HOUT^2]
        float* __restrict__ psum,
        float* __restrict__ psq) {
    constexpr int K    = 9 * CIN;
    constexpr int NTB  = RGP * OCP / 16;
    constexpr int STR  = 2 * RGP + 1;
    constexpr int STC  = 2 * OCP + 1;
    constexpr int CIP  = 36;
    constexpr int MTB  = COUT / 16 / MGN;
    constexpr int NRG  = (HOUT + RG - 1) / RG;
    constexpr int PBLK = BB * NRG;

    __shared__ unsigned short stage[STR * STC * CIP];

    int tid = threadIdx.x;
    int wv = tid >> 6, lane = tid & 63;
    int l15 = lane & 15, lg = lane >> 4;
    int bid = blockIdx.x;
    int b  = bid & 31;
    int t2 = bid >> 5;
    int rg = t2 % NRG;
    int mg = t2 / NRG;
    int co0 = mg * (COUT / MGN);
    int mw = wv % MTB;

    f32x4 acc[NTB];
    #pragma unroll
    for (int i = 0; i < NTB; ++i) acc[i] = (f32x4){0.f, 0.f, 0.f, 0.f};

    const unsigned short* srcb = src + (size_t)b * SR * SC * CIN;
    int srow0 = 2 * rg * RG;

    for (int cb = 0; cb < CIN / 32; ++cb) {
        __syncthreads();
        for (int idx = tid; idx < STR * STC * 16; idx += 256) {
            int ci2 = idx & 15;
            int rc  = idx >> 4;
            int row = rc / STC, col = rc - row * STC;
            int srow = srow0 + row;
            unsigned v = 0;
            if (srow < SR && col < SC)
                v = *(const unsigned*)(srcb + ((size_t)srow * SC + col) * CIN
                                       + cb * 32 + ci2 * 2);
            *(unsigned*)(stage + (row * STC + col) * CIP + ci2 * 2) = v;
        }
        __syncthreads();
        #pragma unroll
        for (int r = 0; r < 9; ++r) {
            int ky = r / 3, kx = r % 3;
            int kk = r * CIN + cb * 32 + lg * 8;
            bf16x8 af = *(const bf16x8*)(wp + (size_t)(co0 + mw * 16 + l15) * K + kk);
            #pragma unroll
            for (int nt = 0; nt < NTB; ++nt) {
                int n = nt * 16 + l15;
                int dy = n / OCP, oxx = n % OCP;
                const unsigned short* sp =
                    stage + ((2 * dy + ky) * STC + (2 * oxx + kx)) * CIP + lg * 8;
                bf16x4 blo = *(const bf16x4*)sp;
                bf16x4 bhi = *(const bf16x4*)(sp + 4);
                bf16x8 bfr;
                bfr[0] = blo[0]; bfr[1] = blo[1]; bfr[2] = blo[2]; bfr[3] = blo[3];
                bfr[4] = bhi[0]; bfr[5] = bhi[1]; bfr[6] = bhi[2]; bfr[7] = bhi[3];
                acc[nt] = __builtin_amdgcn_mfma_f32_16x16x32_bf16(af, bfr, acc[nt], 0, 0, 0);
            }
        }
    }

    // epilogue: write raw out + fused per-block stats partials
    float sa[4] = {0.f, 0.f, 0.f, 0.f}, qa[4] = {0.f, 0.f, 0.f, 0.f};
    #pragma unroll
    for (int nt = 0; nt < NTB; ++nt) {
        int n = nt * 16 + l15;
        int oy = rg * RG + n / OCP, oxx = n % OCP;
        bool act = (oy < HOUT) && (oxx < HOUT);
        #pragma unroll
        for (int q = 0; q < 4; ++q) {
            int co = co0 + mw * 16 + lg * 4 + q;
            float v = act ? (acc[nt][q] + bias[co]) : 0.f;
            if (act)
                out[((size_t)b * COUT + co) * (HOUT * HOUT) + oy * HOUT + oxx] = v;
            sa[q] += v; qa[q] += v * v;
        }
    }
    #pragma unroll
    for (int o = 1; o < 16; o <<= 1) {
        #pragma unroll
        for (int q = 0; q < 4; ++q) {
            sa[q] += __shfl_xor(sa[q], o, 64);
            qa[q] += __shfl_xor(qa[q], o, 64);
        }
    }
    if (l15 == 0) {
        int pblk = b * NRG + rg;
        #pragma unroll
        for (int q = 0; q < 4; ++q) {
            int co = co0 + mw * 16 + lg * 4 + q;
            if (PTRANS) {
                psum[(size_t)pblk * COUT + co] = sa[q];
                psq [(size_t)pblk * COUT + co] = qa[q];
            } else {
                psum[(size_t)co * PBLK + pblk] = sa[q];
                psq [(size_t)co * PBLK + pblk] = qa[q];
            }
        }
    }
}

// ---------------- fold partials -> scale/shift (one block per channel) ------
__global__ __launch_bounds__(256) void stats_fold_kernel(
        const float* __restrict__ psum, const float* __restrict__ psq,
        const float* __restrict__ g, const float* __restrict__ be,
        float* __restrict__ scale, float* __restrict__ shift,
        int PBLK, float count) {
    int c = blockIdx.x;
    float S = 0.f, Q = 0.f;
    for (int p = threadIdx.x; p < PBLK; p += 256) {
        S += psum[(size_t)c * PBLK + p];
        Q += psq[(size_t)c * PBLK + p];
    }
    __shared__ float rs[4], rq[4];
    int lane = threadIdx.x & 63, wv = threadIdx.x >> 6;
    #pragma unroll
    for (int o = 32; o > 0; o >>= 1) {
        S += __shfl_down(S, o, 64);
        Q += __shfl_down(Q, o, 64);
    }
    if (lane == 0) { rs[wv] = S; rq[wv] = Q; }
    __syncthreads();
    if (threadIdx.x == 0) {
        float St = rs[0] + rs[1] + rs[2] + rs[3];
        float Qt = rq[0] + rq[1] + rq[2] + rq[3];
        float mean = St / count;
        float var  = Qt / count - mean * mean;
        float sc   = g[c] * rsqrtf(var + 1e-5f);
        scale[c] = sc;
        shift[c] = be[c] - mean * sc;
    }
}

// ---------------- BN+ReLU + transpose to NHWC bf16 (col-padded) -------------
template<int C, int R, int SCo>
__global__ __launch_bounds__(256) void applyT_kernel(
        const float* __restrict__ raw, const float* __restrict__ scale,
        const float* __restrict__ shift, unsigned short* __restrict__ act) {
    int b = blockIdx.x / R, row = blockIdx.x % R;
    __shared__ float lds[C * (R + 2)];
    for (int idx = threadIdx.x; idx < C * R; idx += 256) {
        int ci = idx / R, col = idx - ci * R;
        float v = fmaxf(fmaf(raw[((size_t)b * C + ci) * (R * R) + row * R + col],
                             scale[ci], shift[ci]), 0.f);
        lds[ci * (R + 2) + col] = v;
    }
    __syncthreads();
    for (int idx = threadIdx.x; idx < SCo * C; idx += 256) {
        int col = idx / C, ci = idx - col * C;
        unsigned short v = 0;
        if (col < R) v = f2b(lds[ci * (R + 2) + col]);
        act[(((size_t)b * R + row) * SCo + col) * C + ci] = v;
    }
}

// ---------------- FC head: fold3 + BN+ReLU + fc1 + (last block) fc2 --------
// conv3 partials are TRANSPOSED: psum[p][c] -> lane=c coalesced reads.
__global__ __launch_bounds__(256) void fc1_kernel(
        const float* __restrict__ out3,   // [B][128][49] raw
        const float* __restrict__ psum,   // [32][128] conv3 partials (transposed)
        const float* __restrict__ psq,
        const float* __restrict__ g3, const float* __restrict__ be3,
        const float* __restrict__ fc1w,   // [64][6272]
        const float* __restrict__ fc1b,
        const float* __restrict__ fc2w,   // [64]
        const float* __restrict__ fc2b,   // [1]
        float* __restrict__ h,            // [B][64]
        int* __restrict__ cnt,            // [B]
        float* __restrict__ outp) {       // [B]
    __shared__ float sc[128], sh[128];
    __shared__ float red[4];
    __shared__ int winner;
    int j = blockIdx.x >> 5;
    int b = blockIdx.x & 31;

    // fold3: lane = channel (coalesced); 32 independent loads per array
    for (int c = threadIdx.x; c < 128; c += 256) {
        float S = 0.f, Q = 0.f;
        #pragma unroll
        for (int p = 0; p < 32; ++p) {
            S += psum[p * 128 + c];
            Q += psq[p * 128 + c];
        }
        const float count = 32.f * 49.f;
        float mean = S / count;
        float var  = Q / count - mean * mean;
        float s = g3[c] * rsqrtf(var + 1e-5f);
        sc[c] = s;
        sh[c] = be3[c] - mean * s;
    }
    __syncthreads();

    const float* ip = out3 + (size_t)b * 6272;
    const float* wp = fc1w + (size_t)j * 6272;
    float s = 0.f;
    for (int i = threadIdx.x; i < 6272; i += 256) {
        int c = i / 49;
        float xv = fmaxf(fmaf(ip[i], sc[c], sh[c]), 0.f);
        s = fmaf(xv, wp[i], s);
    }
    #pragma unroll
    for (int o = 32; o > 0; o >>= 1) s += __shfl_down(s, o, 64);
    if ((threadIdx.x & 63) == 0) red[threadIdx.x >> 6] = s;
    __syncthreads();
    if (threadIdx.x == 0) {
        float t = red[0] + red[1] + red[2] + red[3];
        __hip_atomic_store(&h[b * 64 + j], fmaxf(t + fc1b[j], 0.f),
                           __ATOMIC_RELAXED, __HIP_MEMORY_SCOPE_AGENT);
        __threadfence();
        int old = __hip_atomic_fetch_add(&cnt[b], 1, __ATOMIC_ACQ_REL,
                                         __HIP_MEMORY_SCOPE_AGENT);
        winner = (old == 63) ? 1 : 0;
    }
    __syncthreads();
    if (winner && threadIdx.x < 64) {
        __threadfence();
        float v = __hip_atomic_load(&h[b * 64 + threadIdx.x], __ATOMIC_RELAXED,
                                    __HIP_MEMORY_SCOPE_AGENT) * fc2w[threadIdx.x];
        #pragma unroll
        for (int o = 32; o > 0; o >>= 1) v += __shfl_down(v, o, 64);
        if (threadIdx.x == 0)
            outp[b] = 1.f / (1.f + expf(-(v + fc2b[0])));
    }
}

// ---------------- Launch ----------------
extern "C" void kernel_launch(void* const* d_in, const int* in_sizes, int n_in,
                              void* d_out, int out_size, void* d_ws, size_t ws_size,
                              hipStream_t stream) {
    const float* x       = (const float*)d_in[0];
    const float* conv1_w = (const float*)d_in[1];
    const float* conv1_b = (const float*)d_in[2];
    const float* bn1_g   = (const float*)d_in[3];
    const float* bn1_b   = (const float*)d_in[4];
    const float* conv2_w = (const float*)d_in[5];
    const float* conv2_b = (const float*)d_in[6];
    const float* bn2_g   = (const float*)d_in[7];
    const float* bn2_b   = (const float*)d_in[8];
    const float* conv3_w = (const float*)d_in[9];
    const float* conv3_b = (const float*)d_in[10];
    const float* bn3_g   = (const float*)d_in[11];
    const float* bn3_b   = (const float*)d_in[12];
    const float* fc1_w   = (const float*)d_in[13];
    const float* fc1_b   = (const float*)d_in[14];
    const float* fc2_w   = (const float*)d_in[15];
    const float* fc2_b   = (const float*)d_in[16];
    float* out = (float*)d_out;

    char* wsc = (char*)d_ws;
    size_t o = 0;
    auto alloc = [&](size_t bytes) { char* p = wsc + o; o += (bytes + 255) & ~(size_t)255; return p; };
    unsigned short* laybf  = (unsigned short*)alloc((size_t)BB * 64 * 64 * 64 * 2);
    unsigned short* act1bf = (unsigned short*)alloc((size_t)BB * 31 * 32 * 64 * 2);
    unsigned short* act2bf = (unsigned short*)alloc((size_t)BB * 15 * 16 * 128 * 2);
    unsigned short* wp1    = (unsigned short*)alloc((size_t)64 * 576 * 2);
    unsigned short* wp2    = (unsigned short*)alloc((size_t)128 * 576 * 2);
    unsigned short* wp3    = (unsigned short*)alloc((size_t)128 * 1152 * 2);
    float* out1   = (float*)alloc((size_t)BB * 64 * 961 * 4);
    float* out2   = (float*)alloc((size_t)BB * 128 * 225 * 4);
    float* out3   = (float*)alloc((size_t)BB * 128 * 49 * 4);
    float* psum   = (float*)alloc((size_t)128 * 512 * 4);
    float* psq    = (float*)alloc((size_t)128 * 512 * 4);
    float* scale1 = (float*)alloc(64 * 4);
    float* shift1 = (float*)alloc(64 * 4);
    float* scale2 = (float*)alloc(128 * 4);
    float* shift2 = (float*)alloc(128 * 4);
    float* hbuf   = (float*)alloc((size_t)BB * 64 * 4);
    int*   cnt    = (int*)alloc((size_t)BB * 4);

    // 1) render + weight prepack + cnt reset
    prep_kernel<<<1520, 256, 0, stream>>>(x, laybf, conv1_w, conv2_w, conv3_w,
                                          wp1, wp2, wp3, cnt);

    // 2) conv1 (bf16 NHWC) + fused stats partials. grid 32*16
    gemmconv_kernel<64, 64, 64, 64, 31, 32, 2, 2, 1, false>
        <<<32 * 16, 256, 0, stream>>>(laybf, wp1, conv1_b, out1, psum, psq);
    stats_fold_kernel<<<64, 256, 0, stream>>>(psum, psq, bn1_g, bn1_b,
                                              scale1, shift1, 32 * 16,
                                              (float)(BB * 961));
    applyT_kernel<64, 31, 32><<<BB * 31, 256, 0, stream>>>(out1, scale1, shift1, act1bf);

    // 3) conv2 (bf16 NHWC) + fused stats partials. grid 32*16
    gemmconv_kernel<64, 128, 31, 32, 15, 16, 2, 2, 2, false>
        <<<32 * 16, 256, 0, stream>>>(act1bf, wp2, conv2_b, out2, psum, psq);
    stats_fold_kernel<<<128, 256, 0, stream>>>(psum, psq, bn2_g, bn2_b,
                                               scale2, shift2, 32 * 8,
                                               (float)(BB * 225));
    applyT_kernel<128, 15, 16><<<BB * 15, 256, 0, stream>>>(out2, scale2, shift2, act2bf);

    // 4) conv3 (bf16 NHWC) + fused TRANSPOSED stats partials. grid 32*2
    gemmconv_kernel<128, 128, 15, 16, 7, 8, 7, 8, 2, true>
        <<<32 * 2, 256, 0, stream>>>(act2bf, wp3, conv3_b, out3, psum, psq);

    // 5) FC head: fold3 + fc1 + last-block fc2 in one kernel
    fc1_kernel<<<64 * 32, 256, 0, stream>>>(out3, psum, psq, bn3_g, bn3_b,
                                            fc1_w, fc1_b, fc2_w, fc2_b,
                                            hbuf, cnt, out);
}

// Round 18
// 100.533 us; speedup vs baseline: 1.6804x; 1.6038x over previous
//
#include <hip/hip_runtime.h>
#include <math.h>

#define BB 32

typedef __attribute__((ext_vector_type(8))) short bf16x8;
typedef __attribute__((ext_vector_type(4))) short bf16x4;
typedef __attribute__((ext_vector_type(4))) float f32x4;

__device__ __forceinline__ unsigned short f2b(float x) {
    unsigned u = __float_as_uint(x);
    u += 0x7fffu + ((u >> 16) & 1u);     // RNE; inputs finite
    return (unsigned short)(u >> 16);
}

// ---------------- prep: render NHWC bf16 + prepack all weights --------------
__global__ __launch_bounds__(256) void prep_kernel(
        const float* __restrict__ x, unsigned short* __restrict__ lay,
        const float* __restrict__ w1, const float* __restrict__ w2,
        const float* __restrict__ w3,
        unsigned short* __restrict__ wp1, unsigned short* __restrict__ wp2,
        unsigned short* __restrict__ wp3) {
    int bid = blockIdx.x;
    if (bid < 512) {
        int b = bid >> 4;
        int u = ((bid & 15) << 2) + (threadIdx.x >> 6);
        int n = threadIdx.x & 63;
        const float* xp = x + ((size_t)b * 64 + n) * 20;
        int xL = (int)xp[0], yT = (int)xp[1], xR = (int)xp[2], yB = (int)xp[3];
        float m = xp[4];
        #pragma unroll
        for (int c = 1; c < 16; ++c) m = fmaxf(m, xp[4 + c]);
        unsigned short mu = f2b(m);
        unsigned short* op = lay + (((size_t)b * 64 + u) * 64) * 64 + n;
        #pragma unroll 4
        for (int v = 0; v < 64; ++v) {
            bool vb = (u < 63) && (v < 63) &&
                      (((u == xL || u == xR) && (v > yT && v < yB)) ||
                       ((v == yT || v == yB) && (u > xL && u < xR)));
            op[(size_t)v * 64] = vb ? mu : (unsigned short)0;
        }
    } else {
        int idx = (bid - 512) * 256 + threadIdx.x;
        const int N1 = 64 * 576, N2 = 128 * 576, N3 = 128 * 1152;
        if (idx < N1) {
            int co = idx / 576, k = idx - co * 576;
            int r = k / 64, ci = k - r * 64;
            wp1[idx] = f2b(w1[((size_t)co * 64 + ci) * 9 + r]);
        } else if (idx < N1 + N2) {
            int i2 = idx - N1;
            int co = i2 / 576, k = i2 - co * 576;
            int r = k / 64, ci = k - r * 64;
            wp2[i2] = f2b(w2[((size_t)co * 64 + ci) * 9 + r]);
        } else if (idx < N1 + N2 + N3) {
            int i3 = idx - N1 - N2;
            int co = i3 / 1152, k = i3 - co * 1152;
            int r = k / 128, ci = k - r * 128;
            wp3[i3] = f2b(w3[((size_t)co * 128 + ci) * 9 + r]);
        }
    }
}

// ---------------- MFMA implicit-GEMM conv 3x3 stride-2 VALID ----------------
// src bf16 NHWC [B][SR][SC][CIN]. Epilogue fuses per-block BN stats partials.
// PTRANS: partials stored [PBLK][COUT] (coalesced channel-major consumption).
template<int CIN, int COUT, int SR, int SC, int HOUT, int OCP, int RG,
         int RGP, int MGN, bool PTRANS>
__global__ __launch_bounds__(256) void gemmconv_kernel(
        const unsigned short* __restrict__ src,
        const unsigned short* __restrict__ wp,
        const float* __restrict__ bias,
        float* __restrict__ out,          // f32 raw [B][COUT][HOUT^2]
        float* __restrict__ psum,
        float* __restrict__ psq) {
    constexpr int K    = 9 * CIN;
    constexpr int NTB  = RGP * OCP / 16;
    constexpr int STR  = 2 * RGP + 1;
    constexpr int STC  = 2 * OCP + 1;
    constexpr int CIP  = 36;
    constexpr int MTB  = COUT / 16 / MGN;
    constexpr int NRG  = (HOUT + RG - 1) / RG;
    constexpr int PBLK = BB * NRG;

    __shared__ unsigned short stage[STR * STC * CIP];

    int tid = threadIdx.x;
    int wv = tid >> 6, lane = tid & 63;
    int l15 = lane & 15, lg = lane >> 4;
    int bid = blockIdx.x;
    int b  = bid & 31;
    int t2 = bid >> 5;
    int rg = t2 % NRG;
    int mg = t2 / NRG;
    int co0 = mg * (COUT / MGN);
    int mw = wv % MTB;

    f32x4 acc[NTB];
    #pragma unroll
    for (int i = 0; i < NTB; ++i) acc[i] = (f32x4){0.f, 0.f, 0.f, 0.f};

    const unsigned short* srcb = src + (size_t)b * SR * SC * CIN;
    int srow0 = 2 * rg * RG;

    for (int cb = 0; cb < CIN / 32; ++cb) {
        __syncthreads();
        for (int idx = tid; idx < STR * STC * 16; idx += 256) {
            int ci2 = idx & 15;
            int rc  = idx >> 4;
            int row = rc / STC, col = rc - row * STC;
            int srow = srow0 + row;
            unsigned v = 0;
            if (srow < SR && col < SC)
                v = *(const unsigned*)(srcb + ((size_t)srow * SC + col) * CIN
                                       + cb * 32 + ci2 * 2);
            *(unsigned*)(stage + (row * STC + col) * CIP + ci2 * 2) = v;
        }
        __syncthreads();
        #pragma unroll
        for (int r = 0; r < 9; ++r) {
            int ky = r / 3, kx = r % 3;
            int kk = r * CIN + cb * 32 + lg * 8;
            bf16x8 af = *(const bf16x8*)(wp + (size_t)(co0 + mw * 16 + l15) * K + kk);
            #pragma unroll
            for (int nt = 0; nt < NTB; ++nt) {
                int n = nt * 16 + l15;
                int dy = n / OCP, oxx = n % OCP;
                const unsigned short* sp =
                    stage + ((2 * dy + ky) * STC + (2 * oxx + kx)) * CIP + lg * 8;
                bf16x4 blo = *(const bf16x4*)sp;
                bf16x4 bhi = *(const bf16x4*)(sp + 4);
                bf16x8 bfr;
                bfr[0] = blo[0]; bfr[1] = blo[1]; bfr[2] = blo[2]; bfr[3] = blo[3];
                bfr[4] = bhi[0]; bfr[5] = bhi[1]; bfr[6] = bhi[2]; bfr[7] = bhi[3];
                acc[nt] = __builtin_amdgcn_mfma_f32_16x16x32_bf16(af, bfr, acc[nt], 0, 0, 0);
            }
        }
    }

    // epilogue: write raw out + fused per-block stats partials
    float sa[4] = {0.f, 0.f, 0.f, 0.f}, qa[4] = {0.f, 0.f, 0.f, 0.f};
    #pragma unroll
    for (int nt = 0; nt < NTB; ++nt) {
        int n = nt * 16 + l15;
        int oy = rg * RG + n / OCP, oxx = n % OCP;
        bool act = (oy < HOUT) && (oxx < HOUT);
        #pragma unroll
        for (int q = 0; q < 4; ++q) {
            int co = co0 + mw * 16 + lg * 4 + q;
            float v = act ? (acc[nt][q] + bias[co]) : 0.f;
            if (act)
                out[((size_t)b * COUT + co) * (HOUT * HOUT) + oy * HOUT + oxx] = v;
            sa[q] += v; qa[q] += v * v;
        }
    }
    #pragma unroll
    for (int o = 1; o < 16; o <<= 1) {
        #pragma unroll
        for (int q = 0; q < 4; ++q) {
            sa[q] += __shfl_xor(sa[q], o, 64);
            qa[q] += __shfl_xor(qa[q], o, 64);
        }
    }
    if (l15 == 0) {
        int pblk = b * NRG + rg;
        #pragma unroll
        for (int q = 0; q < 4; ++q) {
            int co = co0 + mw * 16 + lg * 4 + q;
            if (PTRANS) {
                psum[(size_t)pblk * COUT + co] = sa[q];
                psq [(size_t)pblk * COUT + co] = qa[q];
            } else {
                psum[(size_t)co * PBLK + pblk] = sa[q];
                psq [(size_t)co * PBLK + pblk] = qa[q];
            }
        }
    }
}

// ---------------- fold partials -> scale/shift (one block per channel) ------
__global__ __launch_bounds__(256) void stats_fold_kernel(
        const float* __restrict__ psum, const float* __restrict__ psq,
        const float* __restrict__ g, const float* __restrict__ be,
        float* __restrict__ scale, float* __restrict__ shift,
        int PBLK, float count) {
    int c = blockIdx.x;
    float S = 0.f, Q = 0.f;
    for (int p = threadIdx.x; p < PBLK; p += 256) {
        S += psum[(size_t)c * PBLK + p];
        Q += psq[(size_t)c * PBLK + p];
    }
    __shared__ float rs[4], rq[4];
    int lane = threadIdx.x & 63, wv = threadIdx.x >> 6;
    #pragma unroll
    for (int o = 32; o > 0; o >>= 1) {
        S += __shfl_down(S, o, 64);
        Q += __shfl_down(Q, o, 64);
    }
    if (lane == 0) { rs[wv] = S; rq[wv] = Q; }
    __syncthreads();
    if (threadIdx.x == 0) {
        float St = rs[0] + rs[1] + rs[2] + rs[3];
        float Qt = rq[0] + rq[1] + rq[2] + rq[3];
        float mean = St / count;
        float var  = Qt / count - mean * mean;
        float sc   = g[c] * rsqrtf(var + 1e-5f);
        scale[c] = sc;
        shift[c] = be[c] - mean * sc;
    }
}

// ---------------- BN+ReLU + transpose to NHWC bf16 (col-padded) -------------
template<int C, int R, int SCo>
__global__ __launch_bounds__(256) void applyT_kernel(
        const float* __restrict__ raw, const float* __restrict__ scale,
        const float* __restrict__ shift, unsigned short* __restrict__ act) {
    int b = blockIdx.x / R, row = blockIdx.x % R;
    __shared__ float lds[C * (R + 2)];
    for (int idx = threadIdx.x; idx < C * R; idx += 256) {
        int ci = idx / R, col = idx - ci * R;
        float v = fmaxf(fmaf(raw[((size_t)b * C + ci) * (R * R) + row * R + col],
                             scale[ci], shift[ci]), 0.f);
        lds[ci * (R + 2) + col] = v;
    }
    __syncthreads();
    for (int idx = threadIdx.x; idx < SCo * C; idx += 256) {
        int col = idx / C, ci = idx - col * C;
        unsigned short v = 0;
        if (col < R) v = f2b(lds[ci * (R + 2) + col]);
        act[(((size_t)b * R + row) * SCo + col) * C + ci] = v;
    }
}

// ---------------- FC1: fold3 preamble (coalesced) + BN+ReLU + fc1 ----------
__global__ __launch_bounds__(256) void fc1_kernel(
        const float* __restrict__ out3,   // [B][128][49] raw
        const float* __restrict__ psum,   // [32][128] conv3 partials (transposed)
        const float* __restrict__ psq,
        const float* __restrict__ g3, const float* __restrict__ be3,
        const float* __restrict__ fc1w,   // [64][6272]
        const float* __restrict__ fc1b,
        float* __restrict__ h) {          // [B][64]
    __shared__ float sc[128], sh[128];
    __shared__ float red[4];
    int j = blockIdx.x >> 5;
    int b = blockIdx.x & 31;

    // fold3: lane = channel (coalesced)
    for (int c = threadIdx.x; c < 128; c += 256) {
        float S = 0.f, Q = 0.f;
        #pragma unroll
        for (int p = 0; p < 32; ++p) {
            S += psum[p * 128 + c];
            Q += psq[p * 128 + c];
        }
        const float count = 32.f * 49.f;
        float mean = S / count;
        float var  = Q / count - mean * mean;
        float s = g3[c] * rsqrtf(var + 1e-5f);
        sc[c] = s;
        sh[c] = be3[c] - mean * s;
    }
    __syncthreads();

    const float* ip = out3 + (size_t)b * 6272;
    const float* wp = fc1w + (size_t)j * 6272;
    float s = 0.f;
    for (int i = threadIdx.x; i < 6272; i += 256) {
        int c = i / 49;
        float xv = fmaxf(fmaf(ip[i], sc[c], sh[c]), 0.f);
        s = fmaf(xv, wp[i], s);
    }
    #pragma unroll
    for (int o = 32; o > 0; o >>= 1) s += __shfl_down(s, o, 64);
    if ((threadIdx.x & 63) == 0) red[threadIdx.x >> 6] = s;
    __syncthreads();
    if (threadIdx.x == 0) {
        float t = red[0] + red[1] + red[2] + red[3];
        h[b * 64 + j] = fmaxf(t + fc1b[j], 0.f);
    }
}

// ---------------- FC2 + sigmoid ----------------
__global__ __launch_bounds__(64) void fc2_kernel(
        const float* __restrict__ h, const float* __restrict__ fc2w,
        const float* __restrict__ fc2b, float* __restrict__ outp) {
    int b = blockIdx.x;
    float v = h[b * 64 + threadIdx.x] * fc2w[threadIdx.x];
    #pragma unroll
    for (int o = 32; o > 0; o >>= 1) v += __shfl_down(v, o, 64);
    if (threadIdx.x == 0) outp[b] = 1.f / (1.f + expf(-(v + fc2b[0])));
}

// ---------------- Launch ----------------
extern "C" void kernel_launch(void* const* d_in, const int* in_sizes, int n_in,
                              void* d_out, int out_size, void* d_ws, size_t ws_size,
                              hipStream_t stream) {
    const float* x       = (const float*)d_in[0];
    const float* conv1_w = (const float*)d_in[1];
    const float* conv1_b = (const float*)d_in[2];
    const float* bn1_g   = (const float*)d_in[3];
    const float* bn1_b   = (const float*)d_in[4];
    const float* conv2_w = (const float*)d_in[5];
    const float* conv2_b = (const float*)d_in[6];
    const float* bn2_g   = (const float*)d_in[7];
    const float* bn2_b   = (const float*)d_in[8];
    const float* conv3_w = (const float*)d_in[9];
    const float* conv3_b = (const float*)d_in[10];
    const float* bn3_g   = (const float*)d_in[11];
    const float* bn3_b   = (const float*)d_in[12];
    const float* fc1_w   = (const float*)d_in[13];
    const float* fc1_b   = (const float*)d_in[14];
    const float* fc2_w   = (const float*)d_in[15];
    const float* fc2_b   = (const float*)d_in[16];
    float* out = (float*)d_out;

    char* wsc = (char*)d_ws;
    size_t o = 0;
    auto alloc = [&](size_t bytes) { char* p = wsc + o; o += (bytes + 255) & ~(size_t)255; return p; };
    unsigned short* laybf  = (unsigned short*)alloc((size_t)BB * 64 * 64 * 64 * 2);
    unsigned short* act1bf = (unsigned short*)alloc((size_t)BB * 31 * 32 * 64 * 2);
    unsigned short* act2bf = (unsigned short*)alloc((size_t)BB * 15 * 16 * 128 * 2);
    unsigned short* wp1    = (unsigned short*)alloc((size_t)64 * 576 * 2);
    unsigned short* wp2    = (unsigned short*)alloc((size_t)128 * 576 * 2);
    unsigned short* wp3    = (unsigned short*)alloc((size_t)128 * 1152 * 2);
    float* out1   = (float*)alloc((size_t)BB * 64 * 961 * 4);
    float* out2   = (float*)alloc((size_t)BB * 128 * 225 * 4);
    float* out3   = (float*)alloc((size_t)BB * 128 * 49 * 4);
    float* psum   = (float*)alloc((size_t)128 * 512 * 4);
    float* psq    = (float*)alloc((size_t)128 * 512 * 4);
    float* scale1 = (float*)alloc(64 * 4);
    float* shift1 = (float*)alloc(64 * 4);
    float* scale2 = (float*)alloc(128 * 4);
    float* shift2 = (float*)alloc(128 * 4);
    float* hbuf   = (float*)alloc((size_t)BB * 64 * 4);

    // 1) render + weight prepack
    prep_kernel<<<1520, 256, 0, stream>>>(x, laybf, conv1_w, conv2_w, conv3_w,
                                          wp1, wp2, wp3);

    // 2) conv1 (bf16 NHWC) + fused stats partials. grid 32*16
    gemmconv_kernel<64, 64, 64, 64, 31, 32, 2, 2, 1, false>
        <<<32 * 16, 256, 0, stream>>>(laybf, wp1, conv1_b, out1, psum, psq);
    stats_fold_kernel<<<64, 256, 0, stream>>>(psum, psq, bn1_g, bn1_b,
                                              scale1, shift1, 32 * 16,
                                              (float)(BB * 961));
    applyT_kernel<64, 31, 32><<<BB * 31, 256, 0, stream>>>(out1, scale1, shift1, act1bf);

    // 3) conv2 (bf16 NHWC) + fused stats partials. grid 32*16
    gemmconv_kernel<64, 128, 31, 32, 15, 16, 2, 2, 2, false>
        <<<32 * 16, 256, 0, stream>>>(act1bf, wp2, conv2_b, out2, psum, psq);
    stats_fold_kernel<<<128, 256, 0, stream>>>(psum, psq, bn2_g, bn2_b,
                                               scale2, shift2, 32 * 8,
                                               (float)(BB * 225));
    applyT_kernel<128, 15, 16><<<BB * 15, 256, 0, stream>>>(out2, scale2, shift2, act2bf);

    // 4) conv3 (bf16 NHWC) + fused TRANSPOSED stats partials. grid 32*2
    gemmconv_kernel<128, 128, 15, 16, 7, 8, 7, 8, 2, true>
        <<<32 * 2, 256, 0, stream>>>(act2bf, wp3, conv3_b, out3, psum, psq);

    // 5) FC head: fold3 fused into fc1; fc2 separate (no device-scope atomics)
    fc1_kernel<<<64 * 32, 256, 0, stream>>>(out3, psum, psq, bn3_g, bn3_b,
                                            fc1_w, fc1_b, hbuf);
    fc2_kernel<<<BB, 64, 0, stream>>>(hbuf, fc2_w, fc2_b, out);
}